// Round 6
// baseline (144.870 us; speedup 1.0000x reference)
//
#include <hip/hip_runtime.h>
#include <stdint.h>

#define B_ROWS 8192
#define H_DIM 1024
#define L_DIM 1024
#define NH 5
#define YBLK 14   // 1792 rows/head coverage (mean 1365 + 12.7 sigma)

typedef short bf16x8 __attribute__((ext_vector_type(8)));
typedef float f32x4 __attribute__((ext_vector_type(4)));

typedef const __attribute__((address_space(1))) unsigned int* gas_uint_ptr;
typedef __attribute__((address_space(3))) unsigned int* las_uint_ptr;

__device__ __forceinline__ unsigned short f2bf(float f) {
  union { float f; unsigned int u; } v; v.f = f;
  return (unsigned short)((v.u + 0x7FFFu + ((v.u >> 16) & 1u)) >> 16);
}

__device__ __forceinline__ void load_lds16(const void* gsrc, void* ldst) {
  __builtin_amdgcn_global_load_lds((gas_uint_ptr)(uintptr_t)gsrc,
                                   (las_uint_ptr)(uintptr_t)ldst, 16, 0, 0);
}

// ---- kernel 1: fused streaming convert + bucket (proven, unchanged) ----
__global__ void k_conv(const float* __restrict__ hidden, const float* __restrict__ W,
                       const int* __restrict__ group, const int* __restrict__ labels,
                       int* __restrict__ cnt, int* __restrict__ rowlist,
                       unsigned short* __restrict__ Hb, unsigned short* __restrict__ Wb,
                       float* __restrict__ out) {
  const int blk = blockIdx.x;
  const int t = threadIdx.x;
  if (blk < 512) {
    const f32x4* src = (const f32x4*)W;
    ushort4* dst = (ushort4*)Wb;
#pragma unroll
    for (int i = 0; i < 10; i++) {
      int idx = (i * 512 + blk) * 256 + t;
      f32x4 w = __builtin_nontemporal_load(&src[idx]);
      ushort4 o;
      o.x = f2bf(w.x); o.y = f2bf(w.y); o.z = f2bf(w.z); o.w = f2bf(w.w);
      dst[idx] = o;
    }
  } else if (blk < 1536) {
    const int rb = (blk - 512) * 8;
    int gs[8];
#pragma unroll
    for (int r = 0; r < 8; r++) gs[r] = group[rb + r];
#pragma unroll
    for (int r = 0; r < 8; r++) {
      int row = rb + r;
      if (gs[r] == NH) {
        float v = (float)labels[row];
        f32x4 fv; fv.x = v; fv.y = v; fv.z = v; fv.w = v;
        __builtin_nontemporal_store(fv, &((f32x4*)(out + (size_t)row * L_DIM))[t]);
      } else {
        f32x4 h = __builtin_nontemporal_load(&((const f32x4*)(hidden + (size_t)row * H_DIM))[t]);
        ushort4 o;
        o.x = f2bf(h.x); o.y = f2bf(h.y); o.z = f2bf(h.z); o.w = f2bf(h.w);
        ((ushort4*)(Hb + (size_t)row * H_DIM))[t] = o;
      }
    }
  } else {
    __shared__ int lcnt[NH];
    __shared__ int lbase[NH];
    if (t < NH) lcnt[t] = 0;
    __syncthreads();
    int b = (blk - 1536) * 256 + t;
    int g = group[b];
    int lpos = -1;
    if (g < NH) lpos = atomicAdd(&lcnt[g], 1);
    __syncthreads();
    if (t < NH) lbase[t] = atomicAdd(&cnt[t], lcnt[t]);
    __syncthreads();
    if (g < NH) rowlist[g * B_ROWS + lbase[g] + lpos] = b;
  }
}

// ---- kernel 2: 128x128 MFMA GEMM with 3-stage ring + COUNTED vmcnt (T4) ----
// Same proven maps as R0/R5 (128x128 tile, 4 waves 2x2, wave 64x64 = 4x4
// frags, XOR-swizzled gload_lds, 560-block grid). Changes: BK 64->32, THREE
// LDS stages (A+B 48KB -> up to 3 blk/CU), prefetch depth 2, and raw
// s_barrier + s_waitcnt vmcnt(4): the newest stage's 4 loads stay in flight
// ACROSS the barrier (never drained to 0 in the main loop) - removing the
// 16 full vmcnt(0) drains that are the documented ~20% structural stall of
// the 2-stage __syncthreads loop.
// Hazards: RAW - vmcnt(4)+barrier proves stage t complete (its 4 loads are
// the oldest of 8 outstanding). WAR - stage t+2 writes buf[(t+2)%3], whose
// last readers (compute t-1) finished lgkmcnt-waited ds_reads before the
// barrier all waves just crossed. Uniform control flow throughout.
__global__ __launch_bounds__(256, 2)
void k_gemm(const unsigned short* __restrict__ Hb, const unsigned short* __restrict__ Wb,
            const float* __restrict__ bias, const int* __restrict__ cnt,
            const int* __restrict__ rowlist, float* __restrict__ out) {
  const int wgid = blockIdx.x;
  const int xb = wgid & 7;            // same-xb -> same XCD (heuristic)
  const int m = wgid >> 3;
  const int yb = m % YBLK;
  const int head = m / YBLK;

  const int cntg = cnt[head];
  const int rowbase = yb * 128;
  if (rowbase >= cntg) return;
  const int n0 = xb * 128;

  __shared__ __align__(16) unsigned short As[3][128 * 32];  // 3 x 8 KB
  __shared__ __align__(16) unsigned short Bs[3][128 * 32];  // 3 x 8 KB

  const int t = threadIdx.x;
  const int wave = t >> 6, lane = t & 63;
  const int quad = lane >> 4, c16 = lane & 15;
  const int wm = (wave & 1) * 64, wn = (wave >> 1) * 64;

  const unsigned short* Wg = Wb + (size_t)head * L_DIM * H_DIM;
  const int* rl = rowlist + head * B_ROWS;

  // staging sources: 512 chunks of 16B per operand per stage; 2/thread.
  // chunk c: row = c>>2, slot = c&3 holds source col-chunk (c&3)^(row&3).
  const unsigned short* srcA[2];
  const unsigned short* srcB[2];
  int ldso[2];
#pragma unroll
  for (int p = 0; p < 2; p++) {
    int c = p * 256 + t;                  // 0..511
    int row = c >> 2;                     // 0..127
    int ks = ((c & 3) ^ (row & 3)) * 8;   // XOR-swizzled source col (shorts)
    int idx = rowbase + row;
    idx = idx < cntg ? idx : cntg - 1;
    srcA[p] = Hb + (size_t)rl[idx] * H_DIM + ks;
    srcB[p] = Wg + (size_t)(n0 + row) * H_DIM + ks;
    ldso[p] = c * 8;                      // lane-linear LDS dst (shorts)
  }

  f32x4 acc[4][4] = {};

  // 4 loads per stage (A0,B0,A1,B1) -> steady-state wait vmcnt(4)
#define STAGE(buf, kt)                                      \
  {                                                         \
    load_lds16(srcA[0] + (kt), &As[buf][ldso[0]]);          \
    load_lds16(srcB[0] + (kt), &Bs[buf][ldso[0]]);          \
    load_lds16(srcA[1] + (kt), &As[buf][ldso[1]]);          \
    load_lds16(srcB[1] + (kt), &Bs[buf][ldso[1]]);          \
  }

  const int cl = quad ^ (c16 & 3);        // reader slot: row&3 == c16&3

#define COMPUTE(sbuf)                                                     \
  {                                                                       \
    bf16x8 af[4], bf[4];                                                  \
    _Pragma("unroll")                                                     \
    for (int i = 0; i < 4; i++)                                           \
      af[i] = *(const bf16x8*)(&As[sbuf][(wm + i * 16 + c16) * 32 + cl * 8]); \
    _Pragma("unroll")                                                     \
    for (int j = 0; j < 4; j++)                                           \
      bf[j] = *(const bf16x8*)(&Bs[sbuf][(wn + j * 16 + c16) * 32 + cl * 8]); \
    __builtin_amdgcn_s_setprio(1);                                        \
    _Pragma("unroll")                                                     \
    for (int i = 0; i < 4; i++)                                           \
      _Pragma("unroll")                                                   \
      for (int j = 0; j < 4; j++)                                         \
        acc[i][j] = __builtin_amdgcn_mfma_f32_16x16x32_bf16(af[i], bf[j], \
                                                            acc[i][j], 0, 0, 0); \
    __builtin_amdgcn_s_setprio(0);                                        \
  }

  // prologue: stages 0 and 1 in flight (8 outstanding)
  STAGE(0, 0)
  STAGE(1, 32)

  int s = 0;
  for (int kt = 0; kt < 30; ++kt) {       // K-tiles 0..29 (of 32)
    asm volatile("s_waitcnt vmcnt(4)" ::: "memory");  // stage kt ready; kt+1 in flight
    __builtin_amdgcn_s_barrier();
    __builtin_amdgcn_sched_barrier(0);
    int s2 = s + 2; if (s2 >= 3) s2 -= 3;
    STAGE(s2, (kt + 2) * 32)
    COMPUTE(s)
    s = (s + 1 == 3) ? 0 : s + 1;
  }
  // kt=30: outstanding = S(30)+S(31); wait S(30)
  asm volatile("s_waitcnt vmcnt(4)" ::: "memory");
  __builtin_amdgcn_s_barrier();
  __builtin_amdgcn_sched_barrier(0);
  COMPUTE(s)
  s = (s + 1 == 3) ? 0 : s + 1;
  // kt=31: only S(31) outstanding
  asm volatile("s_waitcnt vmcnt(0)" ::: "memory");
  __builtin_amdgcn_s_barrier();
  __builtin_amdgcn_sched_barrier(0);
  COMPUTE(s)

  // epilogue: C/D layout col=lane&15, row=quad*4+reg; scatter via rowlist + bias
  float bv[4];
#pragma unroll
  for (int j = 0; j < 4; j++) bv[j] = bias[head * L_DIM + n0 + wn + j * 16 + c16];
#pragma unroll
  for (int i = 0; i < 4; i++) {
    int rloc0 = wm + i * 16 + quad * 4;
#pragma unroll
    for (int r = 0; r < 4; r++) {
      int idx = rloc0 + r;
      if (rowbase + idx < cntg) {
        int orow = rl[rowbase + idx];
        float* orowp = out + (size_t)orow * L_DIM + n0 + wn;
#pragma unroll
        for (int j = 0; j < 4; j++)
          __builtin_nontemporal_store(acc[i][j][r] + bv[j], &orowp[j * 16 + c16]);
      }
    }
  }
#undef STAGE
#undef COMPUTE
}

extern "C" void kernel_launch(void* const* d_in, const int* in_sizes, int n_in,
                              void* d_out, int out_size, void* d_ws, size_t ws_size,
                              hipStream_t stream) {
  const float* hidden = (const float*)d_in[0];
  const float* W      = (const float*)d_in[1];
  const float* bias   = (const float*)d_in[2];
  const int* group    = (const int*)d_in[3];
  const int* labels   = (const int*)d_in[4];
  float* out = (float*)d_out;

  char* ws = (char*)d_ws;
  int* cnt = (int*)ws;
  int* rowlist = (int*)(ws + 256);
  unsigned short* Wb = (unsigned short*)(ws + (1 << 18));
  unsigned short* Hb = (unsigned short*)(ws + (1 << 18) + (size_t)NH * L_DIM * H_DIM * 2);

  (void)hipMemsetAsync(cnt, 0, 64, stream);
  k_conv<<<1568, 256, 0, stream>>>(hidden, W, group, labels, cnt, rowlist, Hb, Wb, out);
  k_gemm<<<8 * YBLK * NH, 256, 0, stream>>>(Hb, Wb, bias, cnt, rowlist, out);
}

// Round 7
// 128.386 us; speedup vs baseline: 1.1284x; 1.1284x over previous
//
#include <hip/hip_runtime.h>
#include <stdint.h>

#define B_ROWS 8192
#define H_DIM 1024
#define L_DIM 1024
#define NH 5

typedef short bf16x8 __attribute__((ext_vector_type(8)));
typedef float f32x4 __attribute__((ext_vector_type(4)));

typedef const __attribute__((address_space(1))) unsigned int* gas_uint_ptr;
typedef __attribute__((address_space(3))) unsigned int* las_uint_ptr;

__device__ __forceinline__ unsigned short f2bf(float f) {
  union { float f; unsigned int u; } v; v.f = f;
  return (unsigned short)((v.u + 0x7FFFu + ((v.u >> 16) & 1u)) >> 16);
}

__device__ __forceinline__ void load_lds16(const void* gsrc, void* ldst) {
  __builtin_amdgcn_global_load_lds((gas_uint_ptr)(uintptr_t)gsrc,
                                   (las_uint_ptr)(uintptr_t)ldst, 16, 0, 0);
}

// ---- kernel 1: fused streaming convert + bucket (round-7, kept) ----
// blocks [0,512):     W fp32->bf16, grid-stride, 10 float4/thread
// blocks [512,1536):  8 rows/block; g==5 -> fill out with label, else hidden->bf16 Hb
// blocks [1536,1568): bucket rows by group (LDS-aggregated, 5 global atomics/block)
__global__ void k_conv(const float* __restrict__ hidden, const float* __restrict__ W,
                       const int* __restrict__ group, const int* __restrict__ labels,
                       int* __restrict__ cnt, int* __restrict__ rowlist,
                       unsigned short* __restrict__ Hb, unsigned short* __restrict__ Wb,
                       float* __restrict__ out) {
  const int blk = blockIdx.x;
  const int t = threadIdx.x;
  if (blk < 512) {
    const float4* src = (const float4*)W;
    ushort4* dst = (ushort4*)Wb;
#pragma unroll
    for (int i = 0; i < 10; i++) {
      int idx = (i * 512 + blk) * 256 + t;   // 512*256*10 = 1,310,720 float4 = all of W
      float4 w = src[idx];
      ushort4 o;
      o.x = f2bf(w.x); o.y = f2bf(w.y); o.z = f2bf(w.z); o.w = f2bf(w.w);
      dst[idx] = o;
    }
  } else if (blk < 1536) {
    const int rb = (blk - 512) * 8;
    int gs[8];
#pragma unroll
    for (int r = 0; r < 8; r++) gs[r] = group[rb + r];   // independent loads up front
#pragma unroll
    for (int r = 0; r < 8; r++) {
      int row = rb + r;
      if (gs[r] == NH) {
        float v = (float)labels[row];
        ((float4*)(out + (size_t)row * L_DIM))[t] = make_float4(v, v, v, v);
      } else {
        float4 h = ((const float4*)(hidden + (size_t)row * H_DIM))[t];
        ushort4 o;
        o.x = f2bf(h.x); o.y = f2bf(h.y); o.z = f2bf(h.z); o.w = f2bf(h.w);
        ((ushort4*)(Hb + (size_t)row * H_DIM))[t] = o;
      }
    }
  } else {
    __shared__ int lcnt[NH];
    __shared__ int lbase[NH];
    if (t < NH) lcnt[t] = 0;
    __syncthreads();
    int b = (blk - 1536) * 256 + t;
    int g = group[b];
    int lpos = -1;
    if (g < NH) lpos = atomicAdd(&lcnt[g], 1);
    __syncthreads();
    if (t < NH) lbase[t] = atomicAdd(&cnt[t], lcnt[t]);
    __syncthreads();
    if (g < NH) rowlist[g * B_ROWS + lbase[g] + lpos] = b;
  }
}

// ---- kernel 2: bucketed bf16 MFMA GEMM (the measured-best config, restored
// verbatim from the 127.46us baseline) ----
// 128x128 tile, BK=64, double-buffered LDS (64 KB -> 2 blocks/CU), 4 waves
// (2x2), each wave 4x4 frags of 16x16x32 bf16. LDS XOR-swizzle on 16B chunks
// (col cl holds global col cl ^ (row&7)) -> conflict-free ds_read_b128:
// the 8-chunk swizzle spans the full 128B bank period (BK=32's 4-chunk
// variant provably 4-way-conflicts - R6, -15us). Prefetch kt+1 before
// computing kt: the barrier's vmcnt(0) drain overlaps the whole MFMA+ds_read
// phase. Session evidence this is a sharp local optimum: R3 (3-stage 96KB,
// 1blk/CU: -21us), R4 (A-direct from L2: -25us), R6 (BK=32 counted-vmcnt
// ring: -15us). Co-residency (2 blk/CU) + async gload_lds staging beat every
// traffic- or drain-reduction that sacrificed either.
__global__ __launch_bounds__(256, 2)
void k_gemm(const unsigned short* __restrict__ Hb, const unsigned short* __restrict__ Wb,
            const float* __restrict__ bias, const int* __restrict__ cnt,
            const int* __restrict__ rowlist, float* __restrict__ out) {
  const int head = blockIdx.z;
  const int cntg = cnt[head];
  const int rowbase = blockIdx.y * 128;
  if (rowbase >= cntg) return;
  const int n0 = blockIdx.x * 128;

  __shared__ __align__(16) unsigned short As[2][128 * 64];
  __shared__ __align__(16) unsigned short Bs[2][128 * 64];

  const int t = threadIdx.x;
  const int wave = t >> 6, lane = t & 63;
  const int quad = lane >> 4, c16 = lane & 15;
  const int wm = (wave & 1) * 64, wn = (wave >> 1) * 64;

  const unsigned short* Wg = Wb + (size_t)head * L_DIM * H_DIM;
  const int* rl = rowlist + head * B_ROWS;

  // per-thread staging sources (loop-invariant; +kt per iteration)
  const unsigned short* srcA[4];
  const unsigned short* srcB[4];
  int ldso[4];
#pragma unroll
  for (int p = 0; p < 4; p++) {
    int c = p * 256 + t;                  // 16B chunk id 0..1023
    int row = c >> 3;
    int ks = ((c & 7) ^ (row & 7)) * 8;   // XOR-swizzled source column (shorts)
    int idx = rowbase + row;
    idx = idx < cntg ? idx : cntg - 1;    // clamp into valid rowlist entries
    srcA[p] = Hb + (size_t)rl[idx] * H_DIM + ks;
    srcB[p] = Wg + (size_t)(n0 + row) * H_DIM + ks;
    ldso[p] = c * 8;                      // lane-linear LDS dst (shorts)
  }

  f32x4 acc[4][4] = {};

  // prologue: stage tile 0
#pragma unroll
  for (int p = 0; p < 4; p++) {
    load_lds16(srcA[p], &As[0][ldso[p]]);
    load_lds16(srcB[p], &Bs[0][ldso[p]]);
  }
  __syncthreads();

  for (int kt = 0; kt < H_DIM; kt += 64) {
    const int cur = (kt >> 6) & 1;
    if (kt + 64 < H_DIM) {
      const int nxt = cur ^ 1;
#pragma unroll
      for (int p = 0; p < 4; p++) {
        load_lds16(srcA[p] + kt + 64, &As[nxt][ldso[p]]);
        load_lds16(srcB[p] + kt + 64, &Bs[nxt][ldso[p]]);
      }
    }
#pragma unroll
    for (int kk = 0; kk < 64; kk += 32) {
      bf16x8 af[4], bf[4];
      const int sw = c16 & 7;             // row&7 == c16&7 for all frag rows
      const int colb = (kk >> 4) << 1;    // kk=0 -> chunks 0..3, kk=32 -> 4..7
      const int cl = (colb + quad) ^ sw;
#pragma unroll
      for (int i = 0; i < 4; i++) {
        int row = wm + i * 16 + c16;
        af[i] = *(const bf16x8*)(&As[cur][row * 64 + cl * 8]);
      }
#pragma unroll
      for (int j = 0; j < 4; j++) {
        int row = wn + j * 16 + c16;
        bf[j] = *(const bf16x8*)(&Bs[cur][row * 64 + cl * 8]);
      }
#pragma unroll
      for (int i = 0; i < 4; i++)
#pragma unroll
        for (int j = 0; j < 4; j++)
          acc[i][j] = __builtin_amdgcn_mfma_f32_16x16x32_bf16(af[i], bf[j], acc[i][j], 0, 0, 0);
    }
    __syncthreads();   // drains prefetch vmcnt (overlapped with compute above)
  }

  // epilogue: C/D layout col=lane&15, row=quad*4+reg; scatter through rowlist, add bias
#pragma unroll
  for (int i = 0; i < 4; i++) {
    int rloc0 = wm + i * 16 + quad * 4;
#pragma unroll
    for (int r = 0; r < 4; r++) {
      int idx = rloc0 + r;
      if (rowbase + idx < cntg) {
        int orow = rl[rowbase + idx];
        float* orowp = out + (size_t)orow * L_DIM + n0;
#pragma unroll
        for (int j = 0; j < 4; j++) {
          int n = wn + j * 16 + c16;
          orowp[n] = acc[i][j][r] + bias[head * L_DIM + n0 + n];
        }
      }
    }
  }
}

extern "C" void kernel_launch(void* const* d_in, const int* in_sizes, int n_in,
                              void* d_out, int out_size, void* d_ws, size_t ws_size,
                              hipStream_t stream) {
  const float* hidden = (const float*)d_in[0];
  const float* W      = (const float*)d_in[1];
  const float* bias   = (const float*)d_in[2];
  const int* group    = (const int*)d_in[3];
  const int* labels   = (const int*)d_in[4];
  float* out = (float*)d_out;

  // ws layout: [cnt 64B][rowlist 5*8192*4B @256][Wb bf16 @256KB][Hb bf16 after Wb]
  char* ws = (char*)d_ws;
  int* cnt = (int*)ws;
  int* rowlist = (int*)(ws + 256);
  unsigned short* Wb = (unsigned short*)(ws + (1 << 18));
  unsigned short* Hb = (unsigned short*)(ws + (1 << 18) + (size_t)NH * L_DIM * H_DIM * 2);

  hipMemsetAsync(cnt, 0, 64, stream);
  k_conv<<<1568, 256, 0, stream>>>(hidden, W, group, labels, cnt, rowlist, Hb, Wb, out);
  k_gemm<<<dim3(L_DIM / 128, B_ROWS / 128, NH), 256, 0, stream>>>(Hb, Wb, bias, cnt, rowlist, out);
}